// Round 5
// baseline (644.834 us; speedup 1.0000x reference)
//
#include <hip/hip_runtime.h>

#define HD 64      // hidden/feature dim (D == H == 64)
#define PSUB 16    // partial slots per graph (pool accumulation spread)

// ---- bf16 helpers (manual, RNE) ----
__device__ __forceinline__ unsigned short f2bf(float f) {
    union { float f; unsigned u; } v; v.f = f;
    unsigned r = v.u + 0x7FFF + ((v.u >> 16) & 1);
    return (unsigned short)(r >> 16);
}
__device__ __forceinline__ float u2f(unsigned u) {
    union { unsigned u; float f; } v; v.u = u;
    return v.f;
}

// ================= direct-atomic CSR build (3 kernels + 1 memset) =================

// degree histogram via device-scope global atomics
__global__ __launch_bounds__(256) void hist_k(const int* __restrict__ dst,
                                              int* __restrict__ deg, int E)
{
    int stride = gridDim.x * 256;
    for (int i = blockIdx.x * 256 + threadIdx.x; i < E; i += stride)
        atomicAdd(&deg[dst[i]], 1);
}

// single block: exclusive scan of deg -> offsets; dis; gstart binary search
__global__ __launch_bounds__(1024) void scan_k(const int* __restrict__ deg,
    int* __restrict__ offsets, float* __restrict__ dis,
    const int* __restrict__ batch, int* __restrict__ gstart,
    int n, int G, int E)
{
    __shared__ int s[1024];
    int t = threadIdx.x;
    int chunk = (n + 1023) >> 10;
    int b0 = t * chunk;
    int b1 = min(b0 + chunk, n);
    int sum = 0;
    for (int i = b0; i < b1; ++i) sum += deg[i];
    s[t] = sum;
    __syncthreads();
    for (int off = 1; off < 1024; off <<= 1) {
        int u = (t >= off) ? s[t - off] : 0;
        __syncthreads();
        s[t] += u;
        __syncthreads();
    }
    int run = s[t] - sum;            // exclusive prefix of this chunk
    for (int i = b0; i < b1; ++i) {
        int d = deg[i];
        offsets[i] = run;
        dis[i] = rsqrtf(1.0f + (float)d);
        run += d;
    }
    if (t == 0) offsets[n] = E;
    if (t <= G) {
        if (t == G) gstart[t] = n;
        else {
            int lo = 0, hi = n;
            while (lo < hi) { int m = (lo + hi) >> 1; if (batch[m] < t) lo = m + 1; else hi = m; }
            gstart[t] = lo;
        }
    }
}

// scatter edges into CSR slots (order within a node irrelevant for sum)
__global__ __launch_bounds__(256) void scatter_k(const int* __restrict__ src,
    const int* __restrict__ dst, const int* __restrict__ offsets,
    int* __restrict__ cur, int* __restrict__ csr_src, int E)
{
    int stride = gridDim.x * 256;
    for (int i = blockIdx.x * 256 + threadIdx.x; i < E; i += stride) {
        int d = dst[i];
        int pos = offsets[d] + atomicAdd(&cur[d], 1);
        csr_src[pos] = src[i];
    }
}

// ================= layers =================

// register-tiled 64x64 GEMM, bf16 output PREMULTIPLIED by dis[row]:
// outb[r,c] = f2bf(dis[r] * (in @ W)[r,c]).  Row n of outb zeroed.
__global__ __launch_bounds__(256) void gemm64_k(
    const float* __restrict__ in, const float* __restrict__ W,
    const float* __restrict__ dis, unsigned short* __restrict__ outb, int n)
{
    __shared__ float HsT[HD][68];
    __shared__ float Ws[HD][HD];
    int t = threadIdx.x;
    int rowBase = blockIdx.x * 64;

    for (int i = t; i < HD * HD / 4; i += 256)
        ((float4*)Ws)[i] = ((const float4*)W)[i];

    if (blockIdx.x == 0 && t < 64)   // zero pad-row n (gather target for tails)
        outb[(size_t)n * HD + t] = 0;

    {
        int k0 = (t & 15) * 4;
        for (int it = 0; it < 4; ++it) {
            int r = (t >> 4) + it * 16;
            int row = rowBase + r;
            float4 v = make_float4(0.f, 0.f, 0.f, 0.f);
            if (row < n)
                v = *(const float4*)&in[(size_t)row * HD + k0];
            HsT[k0 + 0][r] = v.x;
            HsT[k0 + 1][r] = v.y;
            HsT[k0 + 2][r] = v.z;
            HsT[k0 + 3][r] = v.w;
        }
    }
    __syncthreads();

    int c4 = (t & 15) * 4;
    int r4 = (t >> 4) * 4;
    float acc[4][4];
    #pragma unroll
    for (int i = 0; i < 4; ++i)
        #pragma unroll
        for (int j = 0; j < 4; ++j) acc[i][j] = 0.f;

    #pragma unroll 8
    for (int k = 0; k < HD; ++k) {
        float4 a = *(const float4*)&HsT[k][r4];
        float4 b = *(const float4*)&Ws[k][c4];
        acc[0][0] += a.x * b.x; acc[0][1] += a.x * b.y; acc[0][2] += a.x * b.z; acc[0][3] += a.x * b.w;
        acc[1][0] += a.y * b.x; acc[1][1] += a.y * b.y; acc[1][2] += a.y * b.z; acc[1][3] += a.y * b.w;
        acc[2][0] += a.z * b.x; acc[2][1] += a.z * b.y; acc[2][2] += a.z * b.z; acc[2][3] += a.z * b.w;
        acc[3][0] += a.w * b.x; acc[3][1] += a.w * b.y; acc[3][2] += a.w * b.z; acc[3][3] += a.w * b.w;
    }

    #pragma unroll
    for (int i = 0; i < 4; ++i) {
        int row = rowBase + r4 + i;
        if (row < n) {
            float ds = dis[row];
            ushort4 o;
            o.x = f2bf(ds * acc[i][0]); o.y = f2bf(ds * acc[i][1]);
            o.z = f2bf(ds * acc[i][2]); o.w = f2bf(ds * acc[i][3]);
            *(ushort4*)&outb[(size_t)row * HD + c4] = o;
        }
    }
}

// ---- 4-nodes-per-wave gather core (unchanged, proven) ----
__device__ __forceinline__ void gather4(const unsigned short* __restrict__ hwb,
    const int* __restrict__ offsets, const int* __restrict__ csr_src,
    int node, bool act, int n, int sub, int fl,
    float& a0, float& a1, float& a2, float& a3)
{
    int beg = 0, end = 0;
    if (act) { beg = offsets[node]; end = offsets[node + 1]; }
    int deg = end - beg;
    int md = deg;
    md = max(md, __shfl_xor(md, 16, 64));
    md = max(md, __shfl_xor(md, 32, 64));   // max degree over the wave's 4 nodes

    int nodeC = act ? node : n;             // inactive -> zero row
    uint2 sv = *(const uint2*)(hwb + ((size_t)nodeC << 6) + (fl << 2));
    a0 = u2f(sv.x << 16); a1 = u2f(sv.x & 0xFFFF0000u);
    a2 = u2f(sv.y << 16); a3 = u2f(sv.y & 0xFFFF0000u);

    int base = sub << 4;
    for (int jb = 0; jb < md; jb += 16) {
        int e = jb + fl;
        int idxv = (e < deg) ? csr_src[beg + e] : n;
        {
            uint2 g[8];
            #pragma unroll
            for (int j = 0; j < 8; ++j) {
                int row = __shfl(idxv, base + j, 64);
                g[j] = *(const uint2*)(hwb + ((size_t)row << 6) + (fl << 2));
            }
            #pragma unroll
            for (int j = 0; j < 8; ++j) {
                a0 += u2f(g[j].x << 16); a1 += u2f(g[j].x & 0xFFFF0000u);
                a2 += u2f(g[j].y << 16); a3 += u2f(g[j].y & 0xFFFF0000u);
            }
        }
        if (jb + 8 < md) {
            uint2 g[8];
            #pragma unroll
            for (int j = 0; j < 8; ++j) {
                int row = __shfl(idxv, base + 8 + j, 64);
                g[j] = *(const uint2*)(hwb + ((size_t)row << 6) + (fl << 2));
            }
            #pragma unroll
            for (int j = 0; j < 8; ++j) {
                a0 += u2f(g[j].x << 16); a1 += u2f(g[j].x & 0xFFFF0000u);
                a2 += u2f(g[j].y << 16); a3 += u2f(g[j].y & 0xFFFF0000u);
            }
        }
    }
}

// Fused {agg_l -> relu(+b) -> GEMM W_{l+1} -> *dis -> bf16 table}  (unchanged)
__global__ __launch_bounds__(256) void agg_gemm_k(
    const unsigned short* __restrict__ hwb, const float* __restrict__ dis,
    const int* __restrict__ offsets, const int* __restrict__ csr_src,
    const float* __restrict__ b_prev, const float* __restrict__ W,
    unsigned short* __restrict__ outb, int n)
{
    __shared__ float As[16][68];
    __shared__ float Ws[HD][HD];
    int t    = threadIdx.x;
    int lane = t & 63;
    int sub  = lane >> 4;
    int fl   = lane & 15;
    int w    = t >> 6;
    int nib  = w * 4 + sub;
    int nodeBase = blockIdx.x * 16;
    int node = nodeBase + nib;
    bool act = node < n;

    for (int i = t; i < HD * HD / 4; i += 256)
        ((float4*)Ws)[i] = ((const float4*)W)[i];

    if (blockIdx.x == 0 && t < 64)
        outb[(size_t)n * HD + t] = 0;

    float a0, a1, a2, a3;
    gather4(hwb, offsets, csr_src, node, act, n, sub, fl, a0, a1, a2, a3);

    float ds = act ? dis[node] : 0.f;
    int c0 = fl << 2;
    float4 bb = *(const float4*)&b_prev[c0];
    float4 v;
    v.x = fmaxf(a0 * ds + bb.x, 0.f);
    v.y = fmaxf(a1 * ds + bb.y, 0.f);
    v.z = fmaxf(a2 * ds + bb.z, 0.f);
    v.w = fmaxf(a3 * ds + bb.w, 0.f);
    *(float4*)&As[nib][c0] = v;
    __syncthreads();

    int r  = t & 15;
    int c4 = (t >> 4) << 2;
    float acc0 = 0.f, acc1 = 0.f, acc2 = 0.f, acc3 = 0.f;
    #pragma unroll 4
    for (int k = 0; k < HD; k += 4) {
        float4 a  = *(const float4*)&As[r][k];
        float4 w0 = *(const float4*)&Ws[k + 0][c4];
        float4 w1 = *(const float4*)&Ws[k + 1][c4];
        float4 w2 = *(const float4*)&Ws[k + 2][c4];
        float4 w3 = *(const float4*)&Ws[k + 3][c4];
        acc0 += a.x * w0.x + a.y * w1.x + a.z * w2.x + a.w * w3.x;
        acc1 += a.x * w0.y + a.y * w1.y + a.z * w2.y + a.w * w3.y;
        acc2 += a.x * w0.z + a.y * w1.z + a.z * w2.z + a.w * w3.z;
        acc3 += a.x * w0.w + a.y * w1.w + a.z * w2.w + a.w * w3.w;
    }
    int orow = nodeBase + r;
    if (orow < n) {
        float d2 = dis[orow];
        ushort4 o;
        o.x = f2bf(d2 * acc0); o.y = f2bf(d2 * acc1);
        o.z = f2bf(d2 * acc2); o.w = f2bf(d2 * acc3);
        *(ushort4*)&outb[(size_t)orow * HD + c4] = o;
    }
}

// Layer-3 agg + pool stage 1 + (last block) pool stage 2 + final linear.
__global__ __launch_bounds__(256) void agg_pool4_k(const unsigned short* __restrict__ hwb,
    const float* __restrict__ dis, const int* __restrict__ offsets,
    const int* __restrict__ csr_src, const int* __restrict__ batch,
    float* __restrict__ partial, int* __restrict__ ctr,
    const int* __restrict__ gstart, const float* __restrict__ b3,
    const float* __restrict__ Wl, const float* __restrict__ bl,
    float* __restrict__ out, int n, int O, int G)
{
    __shared__ float sh[16][68];
    __shared__ int gids[16];
    __shared__ int allsame;
    __shared__ int amLast;
    __shared__ float pooled[64][HD + 1];
    int t    = threadIdx.x;
    int lane = t & 63;
    int sub  = lane >> 4;
    int fl   = lane & 15;
    int w    = t >> 6;
    int nib  = w * 4 + sub;
    int node = blockIdx.x * 16 + nib;
    bool act = node < n;

    float a0, a1, a2, a3;
    gather4(hwb, offsets, csr_src, node, act, n, sub, fl, a0, a1, a2, a3);

    float ds = act ? dis[node] : 0.f;
    *(float4*)&sh[nib][fl << 2] = make_float4(a0 * ds, a1 * ds, a2 * ds, a3 * ds);
    if (fl == 0) gids[nib] = act ? batch[node] : -1;
    __syncthreads();

    if (t == 0) {
        int g0 = gids[0];
        int ok = (g0 >= 0);
        #pragma unroll
        for (int r = 1; r < 16; ++r) ok &= (gids[r] == g0);
        allsame = ok;
    }
    __syncthreads();

    int slot = blockIdx.x & (PSUB - 1);
    if (allsame) {
        if (t < 64) {
            float s = 0.f;
            #pragma unroll
            for (int r = 0; r < 16; ++r) s += sh[r][t];
            atomicAdd(&partial[((size_t)gids[0] * PSUB + slot) * HD + t], s);
        }
    } else {
        int c  = t & 63;
        int r0 = w * 4;
        int ga = gids[r0], gb = gids[r0 + 1], gc = gids[r0 + 2], gd = gids[r0 + 3];
        if (ga == gb && gb == gc && gc == gd && ga >= 0) {
            float v = sh[r0][c] + sh[r0 + 1][c] + sh[r0 + 2][c] + sh[r0 + 3][c];
            atomicAdd(&partial[((size_t)ga * PSUB + slot) * HD + c], v);
        } else {
            if (ga >= 0) atomicAdd(&partial[((size_t)ga * PSUB + slot) * HD + c], sh[r0][c]);
            if (gb >= 0) atomicAdd(&partial[((size_t)gb * PSUB + slot) * HD + c], sh[r0 + 1][c]);
            if (gc >= 0) atomicAdd(&partial[((size_t)gc * PSUB + slot) * HD + c], sh[r0 + 2][c]);
            if (gd >= 0) atomicAdd(&partial[((size_t)gd * PSUB + slot) * HD + c], sh[r0 + 3][c]);
        }
    }

    // ---- last-block pool stage 2 ----
    __threadfence();
    if (t == 0) {
        int old = __hip_atomic_fetch_add(ctr, 1, __ATOMIC_ACQ_REL, __HIP_MEMORY_SCOPE_AGENT);
        amLast = (old == (int)gridDim.x - 1);
    }
    __syncthreads();
    if (!amLast) return;

    for (int gb = 0; gb < G; gb += 64) {
        int gcnt = min(64, G - gb);
        for (int idx = t; idx < gcnt * HD; idx += 256) {
            int gl = idx >> 6, c = idx & 63;
            int g = gb + gl;
            float s = 0.f;
            #pragma unroll
            for (int sl = 0; sl < PSUB; ++sl)
                s += __hip_atomic_fetch_add(&partial[((size_t)g * PSUB + sl) * HD + c],
                                            0.0f, __ATOMIC_RELAXED, __HIP_MEMORY_SCOPE_AGENT);
            float cnt = (float)(gstart[g + 1] - gstart[g]);
            pooled[gl][c] = s / cnt + b3[c];
        }
        __syncthreads();
        for (int idx = t; idx < gcnt * O; idx += 256) {
            int gl = idx / O, o = idx - gl * O;
            float acc = bl[o];
            #pragma unroll
            for (int k = 0; k < HD; ++k) acc += pooled[gl][k] * Wl[k * O + o];
            out[(size_t)(gb + gl) * O + o] = acc;
        }
        __syncthreads();
    }
}

extern "C" void kernel_launch(void* const* d_in, const int* in_sizes, int n_in,
                              void* d_out, int out_size, void* d_ws, size_t ws_size,
                              hipStream_t stream)
{
    const float* x    = (const float*)d_in[0];
    const int*   ei   = (const int*)d_in[1];
    const int*   batch= (const int*)d_in[2];
    const float* W1   = (const float*)d_in[3];
    const float* b1   = (const float*)d_in[4];
    const float* W2   = (const float*)d_in[5];
    const float* b2   = (const float*)d_in[6];
    const float* W3   = (const float*)d_in[7];
    const float* b3   = (const float*)d_in[8];
    const float* Wl   = (const float*)d_in[9];
    const float* bl   = (const float*)d_in[10];
    float* out = (float*)d_out;

    const int N = in_sizes[0] / HD;
    const int E = in_sizes[1] / 2;
    const int O = in_sizes[10];
    const int G = out_size / O;

    const int* src = ei;
    const int* dst = ei + E;

    // ---- workspace layout (256 B aligned) ----
    char* p = (char*)d_ws;
    auto take = [&](size_t bytes) { char* r = p; p += (bytes + 255) & ~(size_t)255; return r; };
    int*   csr_src = (int*)  take((size_t)(E + 256) * 4);  // padded for over-read
    int*   offsets = (int*)  take((size_t)(N + 1) * 4);
    float* dis     = (float*)take((size_t)N * 4);
    int*   gstart  = (int*)  take((size_t)(G + 1) * 4);

    // zero-init region (single memset): ctr | deg | cur | partial
    int psz = G * PSUB * HD;
    size_t zbytes = 256 + (size_t)(N + 1) * 4 + (size_t)N * 4 + (size_t)psz * 4;
    char*  zbase  = take(zbytes);
    int*   ctr     = (int*)zbase;
    int*   deg     = (int*)(zbase + 256);
    int*   cur     = deg + (N + 1);
    float* partial = (float*)(cur + N);

    unsigned short* hwb  = (unsigned short*)take((size_t)(N + 1) * HD * 2);  // 6.4 MB (+zero row)
    unsigned short* hwb2 = (unsigned short*)take((size_t)(N + 1) * HD * 2);  // 6.4 MB (+zero row)

    const int TB = 256;
    int nb_edge = min((E + TB - 1) / TB, 2048);
    int nb_gemm = (N + 63) / 64;
    int nb_agg4 = (N + 15) / 16;               // 16 nodes per block (4/wave)

    // ---- CSR build: memset + 3 kernels ----
    hipMemsetAsync(zbase, 0, zbytes, stream);
    hist_k<<<nb_edge, TB, 0, stream>>>(dst, deg, E);
    scan_k<<<1, 1024, 0, stream>>>(deg, offsets, dis, batch, gstart, N, G, E);
    scatter_k<<<nb_edge, TB, 0, stream>>>(src, dst, offsets, cur, csr_src, E);

    // ---- layer 1: x @ W1 -> dis-premult bf16 table ----
    gemm64_k<<<nb_gemm, TB, 0, stream>>>(x, W1, dis, hwb, N);

    // ---- layer 2 fused: agg(hwb) -> relu(+b1) -> @W2 -> hwb2 ----
    agg_gemm_k<<<nb_agg4, TB, 0, stream>>>(hwb, dis, offsets, csr_src, b1, W2, hwb2, N);

    // ---- layer 3 fused: agg(hwb2) -> relu(+b2) -> @W3 -> hwb ----
    agg_gemm_k<<<nb_agg4, TB, 0, stream>>>(hwb2, dis, offsets, csr_src, b2, W3, hwb, N);

    // ---- final agg + pool stage 1 + (last block) stage 2 + linear ----
    agg_pool4_k<<<nb_agg4, TB, 0, stream>>>(hwb, dis, offsets, csr_src, batch,
                                            partial, ctr, gstart, b3, Wl, bl, out, N, O, G);
}

// Round 6
// 193.342 us; speedup vs baseline: 3.3352x; 3.3352x over previous
//
#include <hip/hip_runtime.h>

#define HD 64      // hidden/feature dim (D == H == 64)
#define PSUB 16    // partial slots per graph (pool accumulation spread)
#define NBLK 256   // histogram blocks (edge slices)
#define LOG_NBLK 8
#define NBKT 512   // dst buckets (bucket = dst >> 7, 128 nodes each; N <= 65536)

// ---- bf16 helpers (manual, RNE) ----
__device__ __forceinline__ unsigned short f2bf(float f) {
    union { float f; unsigned u; } v; v.f = f;
    unsigned r = v.u + 0x7FFF + ((v.u >> 16) & 1);
    return (unsigned short)(r >> 16);
}
__device__ __forceinline__ float u2f(unsigned u) {
    union { unsigned u; float f; } v; v.u = u;
    return v.f;
}

// ================= atomic-free bucketed CSR build =================

// also zeroes the pool 'partial' buffer (grid-parallel)
__global__ __launch_bounds__(256) void hist1_k(const int* __restrict__ dst,
                                               int* __restrict__ hist, int E, int chunk,
                                               float* __restrict__ partial, int psz)
{
    __shared__ int lh[NBKT];
    int t = threadIdx.x;
    for (int i = t; i < NBKT; i += 256) lh[i] = 0;
    for (int i = blockIdx.x * 256 + t; i < psz; i += gridDim.x * 256)
        partial[i] = 0.f;
    __syncthreads();
    int base = blockIdx.x * chunk;
    int end  = min(base + chunk, E);
    for (int i = base + t; i < end; i += 256)
        atomicAdd(&lh[dst[i] >> 7], 1);
    __syncthreads();
    for (int i = t; i < NBKT; i += 256)
        hist[blockIdx.x * NBKT + i] = lh[i];
}

// 2a) tile-reduce logical order l = bkt*NBLK + blk  (phys = blk*NBKT + bkt)
__global__ __launch_bounds__(256) void scanA_k(const int* __restrict__ hist,
                                               int* __restrict__ tsum)
{
    __shared__ int s[256];
    int t = threadIdx.x;
    int l = blockIdx.x * 256 + t;
    int phys = (l & (NBLK - 1)) * NBKT + (l >> LOG_NBLK);
    s[t] = hist[phys];
    __syncthreads();
    for (int off = 128; off > 0; off >>= 1) {
        if (t < off) s[t] += s[t + off];
        __syncthreads();
    }
    if (t == 0) tsum[blockIdx.x] = s[0];
}

// 2b) single block: exclusive-scan tsum; compute gstart
__global__ __launch_bounds__(1024) void scanB_k(int* __restrict__ tsum, int nb,
    const int* __restrict__ batch, int* __restrict__ gstart, int n, int G)
{
    __shared__ int s[1024];
    int t = threadIdx.x;
    int v = (t < nb) ? tsum[t] : 0;
    s[t] = v;
    __syncthreads();
    for (int off = 1; off < 1024; off <<= 1) {
        int u = (t >= off) ? s[t - off] : 0;
        __syncthreads();
        s[t] += u;
        __syncthreads();
    }
    if (t < nb) tsum[t] = s[t] - v;
    if (t <= G) {
        if (t == G) gstart[t] = n;
        else {
            int lo = 0, hi = n;
            while (lo < hi) { int m = (lo + hi) >> 1; if (batch[m] < t) lo = m + 1; else hi = m; }
            gstart[t] = lo;
        }
    }
}

__global__ __launch_bounds__(256) void scanC_k(const int* __restrict__ hist,
                                               const int* __restrict__ tsum,
                                               int* __restrict__ scanned)
{
    __shared__ int s[256];
    int t = threadIdx.x;
    int l = blockIdx.x * 256 + t;
    int phys = (l & (NBLK - 1)) * NBKT + (l >> LOG_NBLK);
    int own = hist[phys];
    s[t] = own;
    __syncthreads();
    for (int off = 1; off < 256; off <<= 1) {
        int u = (t >= off) ? s[t - off] : 0;
        __syncthreads();
        s[t] += u;
        __syncthreads();
    }
    scanned[l] = tsum[blockIdx.x] + s[t] - own;
}

// 3) bucket-sorted append of packed (src<<7 | dst&127); per-block private ranges
__global__ __launch_bounds__(256) void append_k(const int* __restrict__ src,
    const int* __restrict__ dst, const int* __restrict__ scanned,
    int* __restrict__ pairs, int E, int chunk)
{
    __shared__ int cur[NBKT];
    int t = threadIdx.x;
    int blk = blockIdx.x;
    for (int i = t; i < NBKT; i += 256) cur[i] = scanned[i * NBLK + blk];
    __syncthreads();
    int base = blk * chunk;
    int end  = min(base + chunk, E);
    for (int i = base + t; i < end; i += 256) {
        int s = src[i], d = dst[i];
        int p = atomicAdd(&cur[d >> 7], 1);
        pairs[p] = (s << 7) | (d & 127);
    }
}

// 4) per-bucket: node counts -> offsets/dis, then in-bucket scatter of csr_src
__global__ __launch_bounds__(256) void bucket_csr_k(const int* __restrict__ pairs,
    const int* __restrict__ scanned, int* __restrict__ offsets,
    float* __restrict__ dis, int* __restrict__ csr_src, int N, int E)
{
    __shared__ int cnt[128];
    __shared__ int sc[128];
    __shared__ int cur[128];
    int t = threadIdx.x;
    int b = blockIdx.x;
    int nodeBase = b * 128;
    int nNodes = min(128, N - nodeBase);
    int bBase = scanned[b * NBLK];
    int bEnd  = (b + 1 < NBKT) ? scanned[(b + 1) * NBLK] : E;

    if (t < 128) cnt[t] = 0;
    __syncthreads();
    for (int i = bBase + t; i < bEnd; i += 256)
        atomicAdd(&cnt[pairs[i] & 127], 1);
    __syncthreads();
    int myc = (t < 128) ? cnt[t] : 0;
    if (t < 128) sc[t] = myc;
    __syncthreads();
    for (int off = 1; off < 128; off <<= 1) {
        int u = (t < 128 && t >= off) ? sc[t - off] : 0;
        __syncthreads();
        if (t < 128) sc[t] += u;
        __syncthreads();
    }
    if (t < 128) {
        int excl = sc[t] - myc;
        cur[t] = excl;
        if (t < nNodes) {
            offsets[nodeBase + t] = bBase + excl;
            dis[nodeBase + t] = rsqrtf(1.0f + (float)myc);
        }
    }
    if (t == 0 && b == gridDim.x - 1) offsets[N] = E;
    __syncthreads();
    for (int i = bBase + t; i < bEnd; i += 256) {
        int pk = pairs[i];
        int pos = bBase + atomicAdd(&cur[pk & 127], 1);
        csr_src[pos] = ((unsigned)pk) >> 7;
    }
}

// ================= layers =================

// register-tiled 64x64 GEMM, bf16 output PREMULTIPLIED by dis[row]:
// outb[r,c] = f2bf(dis[r] * (in @ W)[r,c]).  Row n of outb zeroed.
__global__ __launch_bounds__(256) void gemm64_k(
    const float* __restrict__ in, const float* __restrict__ W,
    const float* __restrict__ dis, unsigned short* __restrict__ outb, int n)
{
    __shared__ float HsT[HD][68];
    __shared__ float Ws[HD][HD];
    int t = threadIdx.x;
    int rowBase = blockIdx.x * 64;

    for (int i = t; i < HD * HD / 4; i += 256)
        ((float4*)Ws)[i] = ((const float4*)W)[i];

    if (blockIdx.x == 0 && t < 64)   // zero pad-row n (gather target for tails)
        outb[(size_t)n * HD + t] = 0;

    {
        int k0 = (t & 15) * 4;
        for (int it = 0; it < 4; ++it) {
            int r = (t >> 4) + it * 16;
            int row = rowBase + r;
            float4 v = make_float4(0.f, 0.f, 0.f, 0.f);
            if (row < n)
                v = *(const float4*)&in[(size_t)row * HD + k0];
            HsT[k0 + 0][r] = v.x;
            HsT[k0 + 1][r] = v.y;
            HsT[k0 + 2][r] = v.z;
            HsT[k0 + 3][r] = v.w;
        }
    }
    __syncthreads();

    int c4 = (t & 15) * 4;
    int r4 = (t >> 4) * 4;
    float acc[4][4];
    #pragma unroll
    for (int i = 0; i < 4; ++i)
        #pragma unroll
        for (int j = 0; j < 4; ++j) acc[i][j] = 0.f;

    #pragma unroll 8
    for (int k = 0; k < HD; ++k) {
        float4 a = *(const float4*)&HsT[k][r4];
        float4 b = *(const float4*)&Ws[k][c4];
        acc[0][0] += a.x * b.x; acc[0][1] += a.x * b.y; acc[0][2] += a.x * b.z; acc[0][3] += a.x * b.w;
        acc[1][0] += a.y * b.x; acc[1][1] += a.y * b.y; acc[1][2] += a.y * b.z; acc[1][3] += a.y * b.w;
        acc[2][0] += a.z * b.x; acc[2][1] += a.z * b.y; acc[2][2] += a.z * b.z; acc[2][3] += a.z * b.w;
        acc[3][0] += a.w * b.x; acc[3][1] += a.w * b.y; acc[3][2] += a.w * b.z; acc[3][3] += a.w * b.w;
    }

    #pragma unroll
    for (int i = 0; i < 4; ++i) {
        int row = rowBase + r4 + i;
        if (row < n) {
            float ds = dis[row];
            ushort4 o;
            o.x = f2bf(ds * acc[i][0]); o.y = f2bf(ds * acc[i][1]);
            o.z = f2bf(ds * acc[i][2]); o.w = f2bf(ds * acc[i][3]);
            *(ushort4*)&outb[(size_t)row * HD + c4] = o;
        }
    }
}

// ---- 4-nodes-per-wave gather core (proven; + next-block index prefetch) ----
// Wave: 4 sub-groups of 16 lanes; sub-group handles one node, lane owns 4 cols.
__device__ __forceinline__ void gather4(const unsigned short* __restrict__ hwb,
    const int* __restrict__ offsets, const int* __restrict__ csr_src,
    int node, bool act, int n, int sub, int fl,
    float& a0, float& a1, float& a2, float& a3)
{
    int beg = 0, end = 0;
    if (act) { beg = offsets[node]; end = offsets[node + 1]; }
    int deg = end - beg;
    int md = deg;
    md = max(md, __shfl_xor(md, 16, 64));
    md = max(md, __shfl_xor(md, 32, 64));   // max degree over the wave's 4 nodes

    int nodeC = act ? node : n;             // inactive -> zero row
    uint2 sv = *(const uint2*)(hwb + ((size_t)nodeC << 6) + (fl << 2));
    a0 = u2f(sv.x << 16); a1 = u2f(sv.x & 0xFFFF0000u);
    a2 = u2f(sv.y << 16); a3 = u2f(sv.y & 0xFFFF0000u);

    int base = sub << 4;
    int idxv = (fl < deg) ? csr_src[beg + fl] : n;       // iteration-0 indices
    for (int jb = 0; jb < md; jb += 16) {
        int e2 = jb + 16 + fl;                           // prefetch next block
        int nidx = (e2 < deg) ? csr_src[beg + e2] : n;   // guarded, never OOB
        {
            uint2 g[8];
            #pragma unroll
            for (int j = 0; j < 8; ++j) {
                int row = __shfl(idxv, base + j, 64);
                g[j] = *(const uint2*)(hwb + ((size_t)row << 6) + (fl << 2));
            }
            #pragma unroll
            for (int j = 0; j < 8; ++j) {
                a0 += u2f(g[j].x << 16); a1 += u2f(g[j].x & 0xFFFF0000u);
                a2 += u2f(g[j].y << 16); a3 += u2f(g[j].y & 0xFFFF0000u);
            }
        }
        if (jb + 8 < md) {
            uint2 g[8];
            #pragma unroll
            for (int j = 0; j < 8; ++j) {
                int row = __shfl(idxv, base + 8 + j, 64);
                g[j] = *(const uint2*)(hwb + ((size_t)row << 6) + (fl << 2));
            }
            #pragma unroll
            for (int j = 0; j < 8; ++j) {
                a0 += u2f(g[j].x << 16); a1 += u2f(g[j].x & 0xFFFF0000u);
                a2 += u2f(g[j].y << 16); a3 += u2f(g[j].y & 0xFFFF0000u);
            }
        }
        idxv = nidx;
    }
}

// Fused {agg_l -> relu(+b) -> GEMM W_{l+1} -> *dis -> bf16 table}
__global__ __launch_bounds__(256) void agg_gemm_k(
    const unsigned short* __restrict__ hwb, const float* __restrict__ dis,
    const int* __restrict__ offsets, const int* __restrict__ csr_src,
    const float* __restrict__ b_prev, const float* __restrict__ W,
    unsigned short* __restrict__ outb, int n)
{
    __shared__ float As[16][68];
    __shared__ float Ws[HD][HD];
    int t    = threadIdx.x;
    int lane = t & 63;
    int sub  = lane >> 4;
    int fl   = lane & 15;
    int w    = t >> 6;
    int nib  = w * 4 + sub;
    int nodeBase = blockIdx.x * 16;
    int node = nodeBase + nib;
    bool act = node < n;

    for (int i = t; i < HD * HD / 4; i += 256)
        ((float4*)Ws)[i] = ((const float4*)W)[i];

    if (blockIdx.x == 0 && t < 64)   // zero pad-row n of OUTPUT table
        outb[(size_t)n * HD + t] = 0;

    float a0, a1, a2, a3;
    gather4(hwb, offsets, csr_src, node, act, n, sub, fl, a0, a1, a2, a3);

    float ds = act ? dis[node] : 0.f;
    int c0 = fl << 2;
    float4 bb = *(const float4*)&b_prev[c0];
    float4 v;
    v.x = fmaxf(a0 * ds + bb.x, 0.f);
    v.y = fmaxf(a1 * ds + bb.y, 0.f);
    v.z = fmaxf(a2 * ds + bb.z, 0.f);
    v.w = fmaxf(a3 * ds + bb.w, 0.f);
    *(float4*)&As[nib][c0] = v;
    __syncthreads();

    int r  = t & 15;
    int c4 = (t >> 4) << 2;
    float acc0 = 0.f, acc1 = 0.f, acc2 = 0.f, acc3 = 0.f;
    #pragma unroll 4
    for (int k = 0; k < HD; k += 4) {
        float4 a  = *(const float4*)&As[r][k];
        float4 w0 = *(const float4*)&Ws[k + 0][c4];
        float4 w1 = *(const float4*)&Ws[k + 1][c4];
        float4 w2 = *(const float4*)&Ws[k + 2][c4];
        float4 w3 = *(const float4*)&Ws[k + 3][c4];
        acc0 += a.x * w0.x + a.y * w1.x + a.z * w2.x + a.w * w3.x;
        acc1 += a.x * w0.y + a.y * w1.y + a.z * w2.y + a.w * w3.y;
        acc2 += a.x * w0.z + a.y * w1.z + a.z * w2.z + a.w * w3.z;
        acc3 += a.x * w0.w + a.y * w1.w + a.z * w2.w + a.w * w3.w;
    }
    int orow = nodeBase + r;
    if (orow < n) {
        float d2 = dis[orow];
        ushort4 o;
        o.x = f2bf(d2 * acc0); o.y = f2bf(d2 * acc1);
        o.z = f2bf(d2 * acc2); o.w = f2bf(d2 * acc3);
        *(ushort4*)&outb[(size_t)orow * HD + c4] = o;
    }
}

// Layer-3 agg fused with pool stage 1.  16 nodes per block; block-level
// fast path (all 16 nodes same graph -> one atomic per column).
__global__ __launch_bounds__(256) void agg_pool4_k(const unsigned short* __restrict__ hwb,
    const float* __restrict__ dis, const int* __restrict__ offsets,
    const int* __restrict__ csr_src, const int* __restrict__ batch,
    float* __restrict__ partial, int n)
{
    __shared__ float sh[16][68];
    __shared__ int gids[16];
    __shared__ int allsame;
    int t    = threadIdx.x;
    int lane = t & 63;
    int sub  = lane >> 4;
    int fl   = lane & 15;
    int w    = t >> 6;
    int nib  = w * 4 + sub;                 // node-in-block 0..15
    int node = blockIdx.x * 16 + nib;
    bool act = node < n;

    float a0, a1, a2, a3;
    gather4(hwb, offsets, csr_src, node, act, n, sub, fl, a0, a1, a2, a3);

    float ds = act ? dis[node] : 0.f;
    *(float4*)&sh[nib][fl << 2] = make_float4(a0 * ds, a1 * ds, a2 * ds, a3 * ds);
    if (fl == 0) gids[nib] = act ? batch[node] : -1;
    __syncthreads();

    if (t == 0) {
        int g0 = gids[0];
        int ok = (g0 >= 0);
        #pragma unroll
        for (int r = 1; r < 16; ++r) ok &= (gids[r] == g0);
        allsame = ok;
    }
    __syncthreads();

    int slot = blockIdx.x & (PSUB - 1);
    if (allsame) {
        if (t < 64) {
            float s = 0.f;
            #pragma unroll
            for (int r = 0; r < 16; ++r) s += sh[r][t];
            atomicAdd(&partial[((size_t)gids[0] * PSUB + slot) * HD + t], s);
        }
    } else {
        int c  = t & 63;
        int r0 = w * 4;
        int ga = gids[r0], gb = gids[r0 + 1], gc = gids[r0 + 2], gd = gids[r0 + 3];
        if (ga == gb && gb == gc && gc == gd && ga >= 0) {
            float v = sh[r0][c] + sh[r0 + 1][c] + sh[r0 + 2][c] + sh[r0 + 3][c];
            atomicAdd(&partial[((size_t)ga * PSUB + slot) * HD + c], v);
        } else {
            if (ga >= 0) atomicAdd(&partial[((size_t)ga * PSUB + slot) * HD + c], sh[r0][c]);
            if (gb >= 0) atomicAdd(&partial[((size_t)gb * PSUB + slot) * HD + c], sh[r0 + 1][c]);
            if (gc >= 0) atomicAdd(&partial[((size_t)gc * PSUB + slot) * HD + c], sh[r0 + 2][c]);
            if (gd >= 0) atomicAdd(&partial[((size_t)gd * PSUB + slot) * HD + c], sh[r0 + 3][c]);
        }
    }
}

// pooling stage 2: reduce partials, mean + b3, final linear
__global__ __launch_bounds__(64) void pool2_k(const float* __restrict__ partial,
    const int* __restrict__ gstart, const float* __restrict__ b3,
    const float* __restrict__ Wl, const float* __restrict__ bl,
    float* __restrict__ out, int O)
{
    __shared__ float pooled[HD];
    int g = blockIdx.x;
    int t = threadIdx.x;
    float sum = 0.0f;
    #pragma unroll
    for (int s = 0; s < PSUB; ++s)
        sum += partial[((size_t)g * PSUB + s) * HD + t];
    float cnt = (float)(gstart[g + 1] - gstart[g]);
    pooled[t] = sum / cnt + b3[t];
    __syncthreads();
    if (t < O) {
        float acc = bl[t];
        #pragma unroll
        for (int k = 0; k < HD; ++k) acc += pooled[k] * Wl[k * O + t];
        out[g * O + t] = acc;
    }
}

extern "C" void kernel_launch(void* const* d_in, const int* in_sizes, int n_in,
                              void* d_out, int out_size, void* d_ws, size_t ws_size,
                              hipStream_t stream)
{
    const float* x    = (const float*)d_in[0];
    const int*   ei   = (const int*)d_in[1];
    const int*   batch= (const int*)d_in[2];
    const float* W1   = (const float*)d_in[3];
    const float* b1   = (const float*)d_in[4];
    const float* W2   = (const float*)d_in[5];
    const float* b2   = (const float*)d_in[6];
    const float* W3   = (const float*)d_in[7];
    const float* b3   = (const float*)d_in[8];
    const float* Wl   = (const float*)d_in[9];
    const float* bl   = (const float*)d_in[10];
    float* out = (float*)d_out;

    const int N = in_sizes[0] / HD;
    const int E = in_sizes[1] / 2;
    const int O = in_sizes[10];
    const int G = out_size / O;

    const int* src = ei;
    const int* dst = ei + E;

    // ---- workspace layout (256 B aligned) ----
    char* p = (char*)d_ws;
    auto take = [&](size_t bytes) { char* r = p; p += (bytes + 255) & ~(size_t)255; return r; };
    int*   csr_src = (int*)  take((size_t)(E + 256) * 4);  // padded for over-read
    int*   offsets = (int*)  take((size_t)(N + 1) * 4);
    float* dis     = (float*)take((size_t)N * 4);
    int*   gstart  = (int*)  take((size_t)(G + 1) * 4);
    float* partial = (float*)take((size_t)G * PSUB * HD * 4);           // 256 KB
    unsigned short* hwb  = (unsigned short*)take((size_t)(N + 1) * HD * 2);  // 6.4 MB (+zero row)
    unsigned short* hwb2 = (unsigned short*)take((size_t)(N + 1) * HD * 2);  // 6.4 MB (+zero row)

    // aliases into regions not yet live during CSR build:
    int* pairs   = (int*)hwb;                  // E*4 = 3.2 MB (packed)
    int* hist    = (int*)hwb2;                 // NBLK*NBKT*4 = 512 KB
    int* scanned = hist + NBLK * NBKT;         // 512 KB
    int* tsum    = scanned + NBLK * NBKT;      // 2 KB

    const int TB = 256;
    int chunk   = (E + NBLK - 1) / NBLK;
    int ntiles  = (NBLK * NBKT) / 256;         // 512
    int nb_gemm = (N + 63) / 64;
    int nb_agg4 = (N + 15) / 16;               // 16 nodes per block (4/wave)
    int nbuck   = (N + 127) / 128;
    int psz     = G * PSUB * HD;

    // ---- CSR build (atomic-free counting sort, packed pairs) ----
    hist1_k<<<NBLK, TB, 0, stream>>>(dst, hist, E, chunk, partial, psz);
    scanA_k<<<ntiles, TB, 0, stream>>>(hist, tsum);
    scanB_k<<<1, 1024, 0, stream>>>(tsum, ntiles, batch, gstart, N, G);
    scanC_k<<<ntiles, TB, 0, stream>>>(hist, tsum, scanned);
    append_k<<<NBLK, TB, 0, stream>>>(src, dst, scanned, pairs, E, chunk);
    bucket_csr_k<<<nbuck, TB, 0, stream>>>(pairs, scanned, offsets, dis, csr_src, N, E);

    // ---- layer 1: x @ W1 -> dis-premult bf16 table ----
    gemm64_k<<<nb_gemm, TB, 0, stream>>>(x, W1, dis, hwb, N);

    // ---- layer 2 fused: agg(hwb) -> relu(+b1) -> @W2 -> hwb2 ----
    agg_gemm_k<<<nb_agg4, TB, 0, stream>>>(hwb, dis, offsets, csr_src, b1, W2, hwb2, N);

    // ---- layer 3 fused: agg(hwb2) -> relu(+b2) -> @W3 -> hwb ----
    agg_gemm_k<<<nb_agg4, TB, 0, stream>>>(hwb2, dis, offsets, csr_src, b2, W3, hwb, N);

    // ---- final agg fused with pool stage 1 ----
    agg_pool4_k<<<nb_agg4, TB, 0, stream>>>(hwb, dis, offsets, csr_src, batch, partial, N);

    // ---- pool stage 2 + final linear ----
    pool2_k<<<G, 64, 0, stream>>>(partial, gstart, b3, Wl, bl, out, O);
}